// Round 11
// baseline (4039.503 us; speedup 1.0000x reference)
//
#include <hip/hip_runtime.h>

// ---------------------------------------------------------------------------
// R11: fused block-specialized pipeline.
//  - prep: weight/state images (identical to R10).
//  - fused kernel, 512 thr: blocks < nscan run the SCAN for chunk k
//    (128 blocks x 32 batch rows; Whh1+Wih2 in 128 accum regs, Whh2 in LDS,
//    g1x C-init; 2 lgkm barriers/step; LDS 155648 B = R7-proven size);
//    blocks >= nscan run FC for chunk k+1 (2x256-thr sub-blocks, 8 tiles
//    grid-stride) into the other g1x slot. fc time hidden under scan.
//  - g1x double-buffered: 2 x 134 MB slots (ws >= 277 MB proven by R9).
//  - 10 launches total: prep, fc0, 7 x fused(scan k || fc k+1), scan7+head.
// ---------------------------------------------------------------------------

typedef unsigned short u16;
typedef short bf16x8 __attribute__((ext_vector_type(8)));
typedef float f32x4 __attribute__((ext_vector_type(4)));
typedef unsigned short u16x4 __attribute__((ext_vector_type(4)));

#define MFMA16(a, b, c) __builtin_amdgcn_mfma_f32_16x16x32_bf16((a), (b), (c), 0, 0, 0)

#define GLOAD_LDS(gp, lp) __builtin_amdgcn_global_load_lds( \
    (const __attribute__((address_space(1))) unsigned int*)(const void*)(gp), \
    (__attribute__((address_space(3))) unsigned int*)(void*)(lp), 16, 0, 0)

#define LGKM_BAR do { \
  asm volatile("s_waitcnt lgkmcnt(0)" ::: "memory"); \
  __builtin_amdgcn_sched_barrier(0); \
  __builtin_amdgcn_s_barrier(); \
  __builtin_amdgcn_sched_barrier(0); \
} while (0)

__device__ __forceinline__ u16 f2bf(float f) {
  union { float f; unsigned u; } v; v.f = f;
  return (u16)((v.u + 0x7FFFu + ((v.u >> 16) & 1u)) >> 16);  // RNE
}
__device__ __forceinline__ float b2f(u16 v) {
  union { unsigned u; float f; } x; x.u = ((unsigned)v) << 16; return x.f;
}
__device__ __forceinline__ float fsig(float x) {
  return __builtin_amdgcn_rcpf(1.0f + __expf(-x));
}
__device__ __forceinline__ float ftanh(float x) {
  return 2.0f * __builtin_amdgcn_rcpf(1.0f + __expf(-2.0f * x)) - 1.0f;
}

// ---- ws layout (u16 / f32 indices) ---------------------------------------
#define WHH1_U  0
#define WIH2_U  65536
#define WHH2_U  131072
#define WIH1_U  196608
#define W1_U    262144
#define W2_U    278528
#define W3_U    311296
#define WO1_U   327680
#define WO2_U   344064
#define WO3_U   376832
#define BS1_F   192512
#define BS2_F   193024
#define STH1_U  393216
#define STH2_U  917504
#define C1_F    720896
#define C2_F    1245184
#define G1X_U   4194304     // slot 0 @ byte 8388608
#define G1X_SLOT 67108864   // u16 per slot (134 MB)
#define TC      32

// ======================= prep (identical to R10) ===========================
__global__ void prep_kernel(const float* __restrict__ Wih1, const float* __restrict__ Whh1,
                            const float* __restrict__ bih1, const float* __restrict__ bhh1,
                            const float* __restrict__ Wih2, const float* __restrict__ Whh2,
                            const float* __restrict__ bih2, const float* __restrict__ bhh2,
                            const float* __restrict__ W_in1, const float* __restrict__ W_in2,
                            const float* __restrict__ W_in3,
                            const float* __restrict__ W_out1, const float* __restrict__ W_out2,
                            const float* __restrict__ W_out3,
                            const float* __restrict__ h1_in, const float* __restrict__ h2_in,
                            const float* __restrict__ c1_in, const float* __restrict__ c2_in,
                            u16* __restrict__ wsu) {
  float* wsf = (float*)wsu;
  const int N_total = 2490368;
  int stride = gridDim.x * blockDim.x;
  for (int idx = blockIdx.x * blockDim.x + threadIdx.x; idx < N_total; idx += stride) {
    if (idx < 385024) {
      int within = idx & 511;
      int f = idx >> 9;
      int lane = within >> 3, e = within & 7;
      int lr = lane & 15, lg = lane >> 4;
      int k8 = lg * 8 + e;
      float v;
      if (f < 128) {
        int kf = f & 3, g = (f >> 2) & 3, w = f >> 4;
        v = Whh1[(g * 128 + w * 16 + lr) * 128 + kf * 32 + k8];
      } else if (f < 256) {
        int ff = f - 128; int kf = ff & 3, g = (ff >> 2) & 3, w = ff >> 4;
        v = Wih2[(g * 128 + w * 16 + lr) * 128 + kf * 32 + k8];
      } else if (f < 384) {
        int ff = f - 256; int kf = ff & 3, g = (ff >> 2) & 3, w = ff >> 4;
        v = Whh2[(g * 128 + w * 16 + lr) * 128 + kf * 32 + k8];
      } else if (f < 512) {
        int ff = f - 384; int kf = ff & 3, n = ff >> 2;
        v = Wih1[(n * 16 + lr) * 128 + kf * 32 + k8];
      } else if (f < 544) {
        int ff = f - 512; int kf = ff & 1, n = ff >> 1;
        v = W_in1[(n * 16 + lr) * 64 + kf * 32 + k8];
      } else if (f < 608) {
        int ff = f - 544; int kf = ff & 7, n = ff >> 3;
        v = W_in2[(n * 16 + lr) * 256 + kf * 32 + k8];
      } else if (f < 640) {
        int ff = f - 608; int kf = ff & 3, n = ff >> 2;
        v = W_in3[(n * 16 + lr) * 128 + kf * 32 + k8];
      } else if (f < 672) {
        int ff = f - 640; int kf = ff & 3, n = ff >> 2;
        v = W_out1[(n * 16 + lr) * 128 + kf * 32 + k8];
      } else if (f < 736) {
        int ff = f - 672; int kf = ff & 3, n = ff >> 2;
        v = W_out2[(n * 16 + lr) * 128 + kf * 32 + k8];
      } else {
        int ff = f - 736; int kf = ff & 7, n = ff >> 3;
        v = W_out3[(n * 16 + lr) * 256 + kf * 32 + k8];
      }
      wsu[idx] = f2bf(v);
    } else if (idx < 385536) {
      int i = idx - 385024; wsf[BS1_F + i] = bih1[i] + bhh1[i];
    } else if (idx < 386048) {
      int i = idx - 385536; wsf[BS2_F + i] = bih2[i] + bhh2[i];
    } else if (idx < 393216) {
    } else if (idx < 917504) {
      int i = idx - 393216; wsu[STH1_U + i] = f2bf(h1_in[i]);
    } else if (idx < 1441792) {
      int i = idx - 917504; wsu[STH2_U + i] = f2bf(h2_in[i]);
    } else if (idx < 1966080) {
      int i = idx - 1441792; wsf[C1_F + i] = c1_in[i];
    } else {
      int i = idx - 1966080; wsf[C2_F + i] = c2_in[i];
    }
  }
}

// ======================= fused kernel ======================================
__global__ __launch_bounds__(512, 1)
void fused_kernel(const float* __restrict__ seq,
                  const float* __restrict__ b_in1, const float* __restrict__ b_in2,
                  const float* __restrict__ b_in3,
                  const float* __restrict__ b_out1, const float* __restrict__ b_out2,
                  const float* __restrict__ b_out3,
                  u16* __restrict__ wsu, float* __restrict__ out,
                  int nscan, int scan_chunk, int fc_chunk, int last) {
  __shared__ u16 SH[77824];   // 155648 B (R7-proven size)
  float* wsf = (float*)wsu;
  const int tid = threadIdx.x;
  const int bid = blockIdx.x;

  if (bid < nscan) {
    // =================== SCAN role: 32 batch rows ========================
    u16* WL  = SH;                       // 65536 u16: Whh2 frags
    u16* H1D = SH + 65536;               // [2][4096]
    u16* H2S = SH + 73728;               // [4096]
    const int wid = tid >> 6, lane = tid & 63;
    const int lr = lane & 15, lg = lane >> 4;
    const int b0 = bid * 32;

    // register weights (128 accum)
    bf16x8 wA[4][4], wB[4][4];
#pragma unroll
    for (int g = 0; g < 4; ++g)
#pragma unroll
      for (int kf = 0; kf < 4; ++kf) {
        size_t fo = (size_t)(((wid * 4 + g) * 4 + kf) * 512) + lane * 8;
        wA[g][kf] = *(const bf16x8*)(wsu + WHH1_U + fo);
        wB[g][kf] = *(const bf16x8*)(wsu + WIH2_U + fo);
      }
#pragma unroll
    for (int g = 0; g < 4; ++g)
#pragma unroll
      for (int kf = 0; kf < 4; ++kf) {
        asm volatile("" : "+a"(wA[g][kf]));
        asm volatile("" : "+a"(wB[g][kf]));
      }
    // Whh2 -> WL
#pragma unroll
    for (int i = 0; i < 16; ++i)
      GLOAD_LDS(wsu + WHH2_U + (wid * 16 + i) * 512 + lane * 8, &WL[(wid * 16 + i) * 512]);

    // state staging: 16B/thread
    const int srow = tid >> 4, sg8 = tid & 15;
    const int sws = (srow * 128 + sg8 * 8) ^ ((srow & 7) << 3);
    *(bf16x8*)&H1D[sws] = *(const bf16x8*)(wsu + STH1_U + (size_t)(b0 + srow) * 128 + sg8 * 8);
    *(bf16x8*)&H2S[sws] = *(const bf16x8*)(wsu + STH2_U + (size_t)(b0 + srow) * 128 + sg8 * 8);
    float cs1[2][4], cs2[2][4], bc2[4];
#pragma unroll
    for (int rt = 0; rt < 2; ++rt)
#pragma unroll
      for (int j = 0; j < 4; ++j) {
        size_t off = (size_t)(b0 + 16 * rt + lg * 4 + j) * 128 + 16 * wid + lr;
        cs1[rt][j] = wsf[C1_F + off];
        cs2[rt][j] = wsf[C2_F + off];
      }
#pragma unroll
    for (int g = 0; g < 4; ++g) bc2[g] = wsf[BS2_F + g * 128 + 16 * wid + lr];

    // g1x base pointer (u16): + tl*2097152 + rt*8192 + g*512 per element
    const u16* gp = wsu + G1X_U + (size_t)(scan_chunk & 1) * G1X_SLOT +
                    (size_t)(2 * bid) * 8192 + lg * 2048 + wid * 64 + lr * 4;
    u16x4 gx[2][4];
#pragma unroll
    for (int rt = 0; rt < 2; ++rt)
#pragma unroll
      for (int g = 0; g < 4; ++g)
        gx[rt][g] = *(const u16x4*)(gp + rt * 8192 + g * 512);

    __syncthreads();   // staging + WL gload_lds drained

    auto frag = [&](const u16* buf, int rt, int kg) -> bf16x8 {
      return *(const bf16x8*)&buf[((16 * rt + lr) * 128 + kg * 8) ^ ((lr & 7) << 3)];
    };

    // ============ 32-step scan: 2 lgkm barriers/step ============
#pragma unroll 2
    for (int tl = 0; tl < TC; ++tl) {
      const int p = tl & 1, q = p ^ 1;
      u16* H1p = H1D + p * 4096;
      u16* H1q = H1D + q * 4096;

      // -- phase 1: cell1 = g1x(t) + Whh1 * h1(t-1), both row-tiles --
      f32x4 acc[2][4];
#pragma unroll
      for (int rt = 0; rt < 2; ++rt)
#pragma unroll
        for (int g = 0; g < 4; ++g)
          acc[rt][g] = (f32x4){ b2f(gx[rt][g][0]), b2f(gx[rt][g][1]),
                                b2f(gx[rt][g][2]), b2f(gx[rt][g][3]) };
      if (tl < TC - 1) {
        const u16* gpt = gp + (size_t)(tl + 1) * 2097152;
#pragma unroll
        for (int rt = 0; rt < 2; ++rt)
#pragma unroll
          for (int g = 0; g < 4; ++g)
            gx[rt][g] = *(const u16x4*)(gpt + rt * 8192 + g * 512);
      }
#pragma unroll
      for (int kf = 0; kf < 4; ++kf) {
        bf16x8 a0 = frag(H1p, 0, kf * 4 + lg);
        bf16x8 a1 = frag(H1p, 1, kf * 4 + lg);
#pragma unroll
        for (int g = 0; g < 4; ++g) {
          acc[0][g] = MFMA16(a0, wA[g][kf], acc[0][g]);
          acc[1][g] = MFMA16(a1, wA[g][kf], acc[1][g]);
        }
      }
#pragma unroll
      for (int rt = 0; rt < 2; ++rt)
#pragma unroll
        for (int j = 0; j < 4; ++j) {
          float cn = fsig(acc[rt][1][j]) * cs1[rt][j] + fsig(acc[rt][0][j]) * ftanh(acc[rt][2][j]);
          cs1[rt][j] = cn;
          int r = 16 * rt + lg * 4 + j;
          H1q[(r * 128 + 16 * wid + lr) ^ ((r & 7) << 3)] = f2bf(fsig(acc[rt][3][j]) * ftanh(cn));
        }
      LGKM_BAR;   // h1(t) visible; all reads of H1p complete

      // -- phase 2: cell2 = bs2 + Wih2*h1(t) + Whh2*h2(t-1) --
      f32x4 acd[2][4];
#pragma unroll
      for (int rt = 0; rt < 2; ++rt)
#pragma unroll
        for (int g = 0; g < 4; ++g)
          acd[rt][g] = (f32x4){ bc2[g], bc2[g], bc2[g], bc2[g] };
#pragma unroll
      for (int kf = 0; kf < 4; ++kf) {
        bf16x8 a0 = frag(H1q, 0, kf * 4 + lg);
        bf16x8 a1 = frag(H1q, 1, kf * 4 + lg);
#pragma unroll
        for (int g = 0; g < 4; ++g) {
          acd[0][g] = MFMA16(a0, wB[g][kf], acd[0][g]);
          acd[1][g] = MFMA16(a1, wB[g][kf], acd[1][g]);
        }
      }
#pragma unroll
      for (int kf = 0; kf < 4; ++kf) {
        bf16x8 h0 = frag(H2S, 0, kf * 4 + lg);
        bf16x8 h1 = frag(H2S, 1, kf * 4 + lg);
#pragma unroll
        for (int g = 0; g < 4; ++g) {
          bf16x8 B = *(const bf16x8*)&WL[(((wid * 4 + g) * 4 + kf) * 512) + lane * 8];
          acd[0][g] = MFMA16(h0, B, acd[0][g]);
          acd[1][g] = MFMA16(h1, B, acd[1][g]);
        }
      }
      u16 hv[2][4];
#pragma unroll
      for (int rt = 0; rt < 2; ++rt)
#pragma unroll
        for (int j = 0; j < 4; ++j) {
          float cn = fsig(acd[rt][1][j]) * cs2[rt][j] + fsig(acd[rt][0][j]) * ftanh(acd[rt][2][j]);
          cs2[rt][j] = cn;
          hv[rt][j] = f2bf(fsig(acd[rt][3][j]) * ftanh(cn));
        }
      LGKM_BAR;   // all reads of H2S complete (H2 single-buffered)
#pragma unroll
      for (int rt = 0; rt < 2; ++rt)
#pragma unroll
        for (int j = 0; j < 4; ++j) {
          int r = 16 * rt + lg * 4 + j;
          H2S[(r * 128 + 16 * wid + lr) ^ ((r & 7) << 3)] = hv[rt][j];
        }
      // next phase2's H2S reads are ordered by next step's first LGKM_BAR
    }
    LGKM_BAR;   // final H1D[0]/H2S writes visible

    if (!last) {
      *(bf16x8*)(wsu + STH1_U + (size_t)(b0 + srow) * 128 + sg8 * 8) = *(const bf16x8*)&H1D[sws];
      *(bf16x8*)(wsu + STH2_U + (size_t)(b0 + srow) * 128 + sg8 * 8) = *(const bf16x8*)&H2S[sws];
#pragma unroll
      for (int rt = 0; rt < 2; ++rt)
#pragma unroll
        for (int j = 0; j < 4; ++j) {
          size_t off = (size_t)(b0 + 16 * rt + lg * 4 + j) * 128 + 16 * wid + lr;
          wsf[C1_F + off] = cs1[rt][j];
          wsf[C2_F + off] = cs2[rt][j];
        }
    } else {
      // ---- head: Y1 -> H1D[1]; Y2 -> H2S(lo)|H1D[0](hi); Y3 -> out ----
      u16* Y1b  = H1D + 4096;
      u16* Y2lo = H2S;
      u16* Y2hi = H1D;
      {
        f32x4 y1[2] = {};
#pragma unroll
        for (int kf = 0; kf < 4; ++kf) {
          bf16x8 B = *(const bf16x8*)(wsu + WO1_U + (size_t)((wid * 4 + kf) * 512) + lane * 8);
          y1[0] = MFMA16(frag(H2S, 0, kf * 4 + lg), B, y1[0]);
          y1[1] = MFMA16(frag(H2S, 1, kf * 4 + lg), B, y1[1]);
        }
        float bo1 = b_out1[wid * 16 + lr];
        LGKM_BAR;
#pragma unroll
        for (int rt = 0; rt < 2; ++rt)
#pragma unroll
          for (int j = 0; j < 4; ++j) {
            int r = 16 * rt + lg * 4 + j;
            Y1b[(r * 128 + 16 * wid + lr) ^ ((r & 7) << 3)] = f2bf(fmaxf(y1[rt][j] + bo1, 0.f));
          }
        LGKM_BAR;
      }
      {
        f32x4 y2[2][2] = {};
#pragma unroll
        for (int kf = 0; kf < 4; ++kf) {
          bf16x8 a0 = frag(Y1b, 0, kf * 4 + lg);
          bf16x8 a1 = frag(Y1b, 1, kf * 4 + lg);
#pragma unroll
          for (int n = 0; n < 2; ++n) {
            bf16x8 B = *(const bf16x8*)(wsu + WO2_U + (size_t)(((2 * wid + n) * 4 + kf) * 512) + lane * 8);
            y2[0][n] = MFMA16(a0, B, y2[0][n]);
            y2[1][n] = MFMA16(a1, B, y2[1][n]);
          }
        }
        LGKM_BAR;   // Y1b reads + old H2S reads complete before overwrite
#pragma unroll
        for (int rt = 0; rt < 2; ++rt)
#pragma unroll
          for (int n = 0; n < 2; ++n)
#pragma unroll
            for (int j = 0; j < 4; ++j) {
              int c = (2 * wid + n) * 16 + lr;
              float v = fmaxf(y2[rt][n][j] + b_out2[c], 0.f);
              u16* buf = (c < 128) ? Y2lo : Y2hi;
              int cc = c & 127, r = 16 * rt + lg * 4 + j;
              buf[(r * 128 + cc) ^ ((r & 7) << 3)] = f2bf(v);
            }
        LGKM_BAR;
      }
      if (wid < 4) {
        int rt = wid >> 1, ci = wid & 1;
        f32x4 y3 = {};
#pragma unroll
        for (int kf = 0; kf < 8; ++kf) {
          const u16* ab = (kf < 4) ? Y2lo : Y2hi;
          bf16x8 A = frag(ab, rt, (kf & 3) * 4 + lg);
          bf16x8 B = *(const bf16x8*)(wsu + WO3_U + (size_t)((ci * 8 + kf) * 512) + lane * 8);
          y3 = MFMA16(A, B, y3);
        }
        float bo3 = b_out3[ci * 16 + lr];
#pragma unroll
        for (int j = 0; j < 4; ++j)
          out[(size_t)(b0 + 16 * rt + lg * 4 + j) * 32 + ci * 16 + lr] = y3[j] + bo3;
      }
    }
  } else {
    // =================== FC role: 2 x 256-thr sub-blocks =================
    const int sub = tid >> 8, stid = tid & 255;
    u16* S = SH + sub * 36864;
    u16* SEQs = S;            // 4096
    u16* F1s  = S + 4096;     // 16384
    u16* F2s  = S + 20480;    // 8192
    u16* XLs  = S + 28672;    // 8192
    const int wid = stid >> 6, lane = stid & 63;
    const int lr = lane & 15, lg = lane >> 4;
    const int t0 = fc_chunk * TC;
    const size_t g1b = (size_t)G1X_U + (size_t)(fc_chunk & 1) * G1X_SLOT;
    const float* bs1f = (const float*)wsu + BS1_F;
    const int nunits = 2 * (gridDim.x - nscan);
    const int unit = (bid - nscan) * 2 + sub;

    for (int tile = unit; tile < 2048; tile += nunits) {
      const int bid_t = tile & 1, bid_b = tile >> 1;
      const int b0c = bid_b * 4, t0c = t0 + bid_t * 16;

      // stage seq rows rho=(b_local*16+t_local)
#pragma unroll
      for (int i = 0; i < 4; ++i) {
        int f = i * 1024 + stid * 4;
        int rho = f >> 6, k = f & 63;
        int b = b0c + (rho >> 4), tt = t0c + (rho & 15);
        float4 v = *(const float4*)(seq + ((size_t)b * 256 + tt) * 64 + k);
        u16x4 o = { f2bf(v.x), f2bf(v.y), f2bf(v.z), f2bf(v.w) };
        *(u16x4*)&SEQs[(rho * 64 + k) ^ ((rho & 7) << 3)] = o;
      }
      __syncthreads();

      { // L1: [64,256], K=64
        f32x4 a1[4][4] = {};
#pragma unroll
        for (int kf = 0; kf < 2; ++kf) {
          bf16x8 A[4];
#pragma unroll
          for (int rt = 0; rt < 4; ++rt) {
            int r = 16 * rt + lr;
            A[rt] = *(const bf16x8*)&SEQs[(r * 64 + (kf * 4 + lg) * 8) ^ ((r & 7) << 3)];
          }
#pragma unroll
          for (int n = 0; n < 4; ++n) {
            bf16x8 B = *(const bf16x8*)(wsu + W1_U + (size_t)(((4 * wid + n) * 2 + kf) * 512) + lane * 8);
#pragma unroll
            for (int rt = 0; rt < 4; ++rt) a1[rt][n] = MFMA16(A[rt], B, a1[rt][n]);
          }
        }
#pragma unroll
        for (int n = 0; n < 4; ++n) {
          float bb = b_in1[(4 * wid + n) * 16 + lr];
#pragma unroll
          for (int rt = 0; rt < 4; ++rt)
#pragma unroll
            for (int j = 0; j < 4; ++j) {
              int r = 16 * rt + lg * 4 + j, c = (4 * wid + n) * 16 + lr;
              F1s[(r * 256 + c) ^ ((r & 7) << 3)] = f2bf(fmaxf(a1[rt][n][j] + bb, 0.f));
            }
        }
      }
      __syncthreads();

      { // L2: [64,128], K=256
        f32x4 a2[4][2] = {};
#pragma unroll
        for (int kf = 0; kf < 8; ++kf) {
          bf16x8 A[4];
#pragma unroll
          for (int rt = 0; rt < 4; ++rt) {
            int r = 16 * rt + lr;
            A[rt] = *(const bf16x8*)&F1s[(r * 256 + (kf * 4 + lg) * 8) ^ ((r & 7) << 3)];
          }
#pragma unroll
          for (int n = 0; n < 2; ++n) {
            bf16x8 B = *(const bf16x8*)(wsu + W2_U + (size_t)(((2 * wid + n) * 8 + kf) * 512) + lane * 8);
#pragma unroll
            for (int rt = 0; rt < 4; ++rt) a2[rt][n] = MFMA16(A[rt], B, a2[rt][n]);
          }
        }
#pragma unroll
        for (int n = 0; n < 2; ++n) {
          float bb = b_in2[(2 * wid + n) * 16 + lr];
#pragma unroll
          for (int rt = 0; rt < 4; ++rt)
#pragma unroll
            for (int j = 0; j < 4; ++j) {
              int r = 16 * rt + lg * 4 + j, c = (2 * wid + n) * 16 + lr;
              F2s[(r * 128 + c) ^ ((r & 7) << 3)] = f2bf(fmaxf(a2[rt][n][j] + bb, 0.f));
            }
        }
      }
      __syncthreads();

      { // L3: [64,128], K=128 -> XLs
        f32x4 a3[4][2] = {};
#pragma unroll
        for (int kf = 0; kf < 4; ++kf) {
          bf16x8 A[4];
#pragma unroll
          for (int rt = 0; rt < 4; ++rt) {
            int r = 16 * rt + lr;
            A[rt] = *(const bf16x8*)&F2s[(r * 128 + (kf * 4 + lg) * 8) ^ ((r & 7) << 3)];
          }
#pragma unroll
          for (int n = 0; n < 2; ++n) {
            bf16x8 B = *(const bf16x8*)(wsu + W3_U + (size_t)(((2 * wid + n) * 4 + kf) * 512) + lane * 8);
#pragma unroll
            for (int rt = 0; rt < 4; ++rt) a3[rt][n] = MFMA16(A[rt], B, a3[rt][n]);
          }
        }
#pragma unroll
        for (int n = 0; n < 2; ++n) {
          float bb = b_in3[(2 * wid + n) * 16 + lr];
#pragma unroll
          for (int rt = 0; rt < 4; ++rt)
#pragma unroll
            for (int j = 0; j < 4; ++j) {
              int r = 16 * rt + lg * 4 + j, c = (2 * wid + n) * 16 + lr;
              XLs[(r * 128 + c) ^ ((r & 7) << 3)] = f2bf(fmaxf(a3[rt][n][j] + bb, 0.f));
            }
        }
      }
      __syncthreads();

      { // L4: g1x = x @ Wih1^T + bs1 -> global (fragment order)
        f32x4 a4[4][8] = {};
#pragma unroll
        for (int kf = 0; kf < 4; ++kf) {
          bf16x8 A[4];
#pragma unroll
          for (int rt = 0; rt < 4; ++rt) {
            int r = 16 * rt + lr;
            A[rt] = *(const bf16x8*)&XLs[(r * 128 + (kf * 4 + lg) * 8) ^ ((r & 7) << 3)];
          }
#pragma unroll
          for (int n = 0; n < 8; ++n) {
            bf16x8 B = *(const bf16x8*)(wsu + WIH1_U + (size_t)(((wid * 8 + n) * 4 + kf) * 512) + lane * 8);
#pragma unroll
            for (int rt = 0; rt < 4; ++rt) a4[rt][n] = MFMA16(A[rt], B, a4[rt][n]);
          }
        }
        const int blk = bid_b >> 2, slg = bid_b & 3;
#pragma unroll
        for (int n = 0; n < 8; ++n) {
          float bb = bs1f[(wid * 8 + n) * 16 + lr];
#pragma unroll
          for (int j = 0; j < 4; ++j) {
            int tl = bid_t * 16 + lg * 4 + j;
            u16x4 o = { f2bf(a4[0][n][j] + bb), f2bf(a4[1][n][j] + bb),
                        f2bf(a4[2][n][j] + bb), f2bf(a4[3][n][j] + bb) };
            size_t au = g1b +
                ((((((size_t)tl * 256 + blk) * 4 + slg) * 4 + wid) * 8 + n) * 16 + lr) * 4;
            *(u16x4*)(wsu + au) = o;
          }
        }
      }
      __syncthreads();   // XLs reads done before next tile's stores
    }
  }
}

// ======================= host ==============================================
extern "C" void kernel_launch(void* const* d_in, const int* in_sizes, int n_in,
                              void* d_out, int out_size, void* d_ws, size_t ws_size,
                              hipStream_t stream) {
  (void)in_sizes; (void)n_in; (void)out_size; (void)ws_size;
  const float* seq    = (const float*)d_in[0];
  const float* h1     = (const float*)d_in[1];
  const float* c1     = (const float*)d_in[2];
  const float* h2     = (const float*)d_in[3];
  const float* c2     = (const float*)d_in[4];
  const float* W_in1  = (const float*)d_in[5];
  const float* b_in1  = (const float*)d_in[6];
  const float* W_in2  = (const float*)d_in[7];
  const float* b_in2  = (const float*)d_in[8];
  const float* W_in3  = (const float*)d_in[9];
  const float* b_in3  = (const float*)d_in[10];
  const float* Wih1   = (const float*)d_in[11];
  const float* Whh1   = (const float*)d_in[12];
  const float* bih1   = (const float*)d_in[13];
  const float* bhh1   = (const float*)d_in[14];
  const float* Wih2   = (const float*)d_in[15];
  const float* Whh2   = (const float*)d_in[16];
  const float* bih2   = (const float*)d_in[17];
  const float* bhh2   = (const float*)d_in[18];
  const float* W_out1 = (const float*)d_in[19];
  const float* b_out1 = (const float*)d_in[20];
  const float* W_out2 = (const float*)d_in[21];
  const float* b_out2 = (const float*)d_in[22];
  const float* W_out3 = (const float*)d_in[23];
  const float* b_out3 = (const float*)d_in[24];
  u16* wsu = (u16*)d_ws;
  float* out = (float*)d_out;

  hipLaunchKernelGGL(prep_kernel, dim3(512), dim3(256), 0, stream,
                     Wih1, Whh1, bih1, bhh1, Wih2, Whh2, bih2, bhh2,
                     W_in1, W_in2, W_in3, W_out1, W_out2, W_out3,
                     h1, h2, c1, c2, wsu);
  // L1: fc chunk 0 only
  hipLaunchKernelGGL(fused_kernel, dim3(128), dim3(512), 0, stream,
                     seq, b_in1, b_in2, b_in3, b_out1, b_out2, b_out3,
                     wsu, out, 0, 0, 0, 0);
  // L2..L8: scan chunk k || fc chunk k+1
  for (int k = 0; k < 7; ++k)
    hipLaunchKernelGGL(fused_kernel, dim3(256), dim3(512), 0, stream,
                       seq, b_in1, b_in2, b_in3, b_out1, b_out2, b_out3,
                       wsu, out, 128, k, k + 1, 0);
  // L9: scan chunk 7 + head
  hipLaunchKernelGGL(fused_kernel, dim3(128), dim3(512), 0, stream,
                     seq, b_in1, b_in2, b_in3, b_out1, b_out2, b_out3,
                     wsu, out, 128, 7, 0, 1);
}

// Round 12
// 1617.471 us; speedup vs baseline: 2.4974x; 2.4974x over previous
//
#include <hip/hip_runtime.h>

// ---------------------------------------------------------------------------
// R12: R10 structure, de-rematerialized.
//  - fc_chunk: x = fc_in(seq) AND g1x = x@Wih1^T + bs1 per 64-step chunk.
//  - scan_chunk: 256 blocks x 512 thr, 16 batch rows, 64 steps. Whh1+Wih2 in
//    128 accum regs ("+a"), Whh2 in LDS, g1x as MFMA C-init. Arch pressure
//    reduced (streamed A-frags, inline h-stores) so the gx prefetch is not
//    rematerialized (R10: FETCH showed g1x read ~2x = remat at use). gx
//    pinned "+v" at end of phase2. 1 lgkm barrier/step.
//  - TC=64, NCH=4: g1x slot 268.4MB; ws need 276.8MB (proven by R9 nch=1).
// ---------------------------------------------------------------------------

typedef unsigned short u16;
typedef short bf16x8 __attribute__((ext_vector_type(8)));
typedef float f32x4 __attribute__((ext_vector_type(4)));
typedef unsigned short u16x4 __attribute__((ext_vector_type(4)));

#define MFMA16(a, b, c) __builtin_amdgcn_mfma_f32_16x16x32_bf16((a), (b), (c), 0, 0, 0)

#define GLOAD_LDS(gp, lp) __builtin_amdgcn_global_load_lds( \
    (const __attribute__((address_space(1))) unsigned int*)(const void*)(gp), \
    (__attribute__((address_space(3))) unsigned int*)(void*)(lp), 16, 0, 0)

#define LGKM_BAR do { \
  asm volatile("s_waitcnt lgkmcnt(0)" ::: "memory"); \
  __builtin_amdgcn_sched_barrier(0); \
  __builtin_amdgcn_s_barrier(); \
  __builtin_amdgcn_sched_barrier(0); \
} while (0)

__device__ __forceinline__ u16 f2bf(float f) {
  union { float f; unsigned u; } v; v.f = f;
  return (u16)((v.u + 0x7FFFu + ((v.u >> 16) & 1u)) >> 16);  // RNE
}
__device__ __forceinline__ float b2f(u16 v) {
  union { unsigned u; float f; } x; x.u = ((unsigned)v) << 16; return x.f;
}
__device__ __forceinline__ float fsig(float x) {
  return __builtin_amdgcn_rcpf(1.0f + __expf(-x));
}
__device__ __forceinline__ float ftanh(float x) {
  return 2.0f * __builtin_amdgcn_rcpf(1.0f + __expf(-2.0f * x)) - 1.0f;
}

// ---- ws layout (u16 / f32 indices) ---------------------------------------
#define WHH1_U  0         // 128 frags ((w*4+g)*4+kf)*512 : Whh1
#define WIH2_U  65536     // 128 frags : Wih2
#define WHH2_U  131072    // 128 frags : Whh2 (LDS image)
#define WIH1_U  196608    // 128 frags (n*4+kf)*512 : Wih1 (fc L4)
#define W1_U    262144    // 32 frags (n*2+kf)
#define W2_U    278528    // 64 frags (n*8+kf)
#define W3_U    311296    // 32 frags (n*4+kf)
#define WO1_U   327680
#define WO2_U   344064
#define WO3_U   376832
#define BS1_F   192512
#define BS2_F   193024
#define STH1_U  393216
#define STH2_U  917504
#define C1_F    720896
#define C2_F    1245184
#define G1X_U   4194304   // g1x chunk buffer @ byte 8388608, 268.4 MB (TC=64)
#define TC      64
#define NCH     4

// g1x u16 index: (((((tl*256+blk)*4+slg)*4+g)*8+swid)*16+slr)*4 + sj

// ======================= prep ==============================================
__global__ void prep_kernel(const float* __restrict__ Wih1, const float* __restrict__ Whh1,
                            const float* __restrict__ bih1, const float* __restrict__ bhh1,
                            const float* __restrict__ Wih2, const float* __restrict__ Whh2,
                            const float* __restrict__ bih2, const float* __restrict__ bhh2,
                            const float* __restrict__ W_in1, const float* __restrict__ W_in2,
                            const float* __restrict__ W_in3,
                            const float* __restrict__ W_out1, const float* __restrict__ W_out2,
                            const float* __restrict__ W_out3,
                            const float* __restrict__ h1_in, const float* __restrict__ h2_in,
                            const float* __restrict__ c1_in, const float* __restrict__ c2_in,
                            u16* __restrict__ wsu) {
  float* wsf = (float*)wsu;
  const int N_total = 2490368;
  int stride = gridDim.x * blockDim.x;
  for (int idx = blockIdx.x * blockDim.x + threadIdx.x; idx < N_total; idx += stride) {
    if (idx < 385024) {
      int within = idx & 511;
      int f = idx >> 9;
      int lane = within >> 3, e = within & 7;
      int lr = lane & 15, lg = lane >> 4;
      int k8 = lg * 8 + e;
      float v;
      if (f < 128) {
        int kf = f & 3, g = (f >> 2) & 3, w = f >> 4;
        v = Whh1[(g * 128 + w * 16 + lr) * 128 + kf * 32 + k8];
      } else if (f < 256) {
        int ff = f - 128; int kf = ff & 3, g = (ff >> 2) & 3, w = ff >> 4;
        v = Wih2[(g * 128 + w * 16 + lr) * 128 + kf * 32 + k8];
      } else if (f < 384) {
        int ff = f - 256; int kf = ff & 3, g = (ff >> 2) & 3, w = ff >> 4;
        v = Whh2[(g * 128 + w * 16 + lr) * 128 + kf * 32 + k8];
      } else if (f < 512) {
        int ff = f - 384; int kf = ff & 3, n = ff >> 2;
        v = Wih1[(n * 16 + lr) * 128 + kf * 32 + k8];
      } else if (f < 544) {
        int ff = f - 512; int kf = ff & 1, n = ff >> 1;
        v = W_in1[(n * 16 + lr) * 64 + kf * 32 + k8];
      } else if (f < 608) {
        int ff = f - 544; int kf = ff & 7, n = ff >> 3;
        v = W_in2[(n * 16 + lr) * 256 + kf * 32 + k8];
      } else if (f < 640) {
        int ff = f - 608; int kf = ff & 3, n = ff >> 2;
        v = W_in3[(n * 16 + lr) * 128 + kf * 32 + k8];
      } else if (f < 672) {
        int ff = f - 640; int kf = ff & 3, n = ff >> 2;
        v = W_out1[(n * 16 + lr) * 128 + kf * 32 + k8];
      } else if (f < 736) {
        int ff = f - 672; int kf = ff & 3, n = ff >> 2;
        v = W_out2[(n * 16 + lr) * 128 + kf * 32 + k8];
      } else {
        int ff = f - 736; int kf = ff & 7, n = ff >> 3;
        v = W_out3[(n * 16 + lr) * 256 + kf * 32 + k8];
      }
      wsu[idx] = f2bf(v);
    } else if (idx < 385536) {
      int i = idx - 385024; wsf[BS1_F + i] = bih1[i] + bhh1[i];
    } else if (idx < 386048) {
      int i = idx - 385536; wsf[BS2_F + i] = bih2[i] + bhh2[i];
    } else if (idx < 393216) {
      // pad
    } else if (idx < 917504) {
      int i = idx - 393216; wsu[STH1_U + i] = f2bf(h1_in[i]);
    } else if (idx < 1441792) {
      int i = idx - 917504; wsu[STH2_U + i] = f2bf(h2_in[i]);
    } else if (idx < 1966080) {
      int i = idx - 1441792; wsf[C1_F + i] = c1_in[i];
    } else {
      int i = idx - 1966080; wsf[C2_F + i] = c2_in[i];
    }
  }
}

// ======================= fc chunk ==========================================
// 4096 blocks (1024 b-groups x 4 t-quarters) x 256 thr; block = 4 b x 16 t.
__global__ __launch_bounds__(256, 2)
void fc_chunk(const float* __restrict__ seq,
              const float* __restrict__ b_in1, const float* __restrict__ b_in2,
              const float* __restrict__ b_in3,
              u16* __restrict__ wsu, int t0) {
  __shared__ u16 SEQs[4096];   // [64][64]
  __shared__ u16 F1s[16384];   // [64][256]
  __shared__ u16 F2s[8192];    // [64][128]
  __shared__ u16 XLs[8192];    // [64][128]
  const int tid = threadIdx.x;
  const int wid = tid >> 6, lane = tid & 63;
  const int lr = lane & 15, lg = lane >> 4;
  const int bid_t = blockIdx.x & 3, bid_b = blockIdx.x >> 2;
  const int b0c = bid_b * 4, t0c = t0 + bid_t * 16;
  const float* bs1f = (const float*)wsu + BS1_F;

#pragma unroll
  for (int i = 0; i < 4; ++i) {
    int f = i * 1024 + tid * 4;
    int rho = f >> 6, k = f & 63;
    int b = b0c + (rho >> 4), tt = t0c + (rho & 15);
    float4 v = *(const float4*)(seq + ((size_t)b * 256 + tt) * 64 + k);
    u16x4 o = { f2bf(v.x), f2bf(v.y), f2bf(v.z), f2bf(v.w) };
    *(u16x4*)&SEQs[(rho * 64 + k) ^ ((rho & 7) << 3)] = o;
  }
  __syncthreads();

  { // L1: [64,256], K=64
    f32x4 a1[4][4] = {};
#pragma unroll
    for (int kf = 0; kf < 2; ++kf) {
      bf16x8 A[4];
#pragma unroll
      for (int rt = 0; rt < 4; ++rt) {
        int r = 16 * rt + lr;
        A[rt] = *(const bf16x8*)&SEQs[(r * 64 + (kf * 4 + lg) * 8) ^ ((r & 7) << 3)];
      }
#pragma unroll
      for (int n = 0; n < 4; ++n) {
        bf16x8 B = *(const bf16x8*)(wsu + W1_U + (size_t)(((4 * wid + n) * 2 + kf) * 512) + lane * 8);
#pragma unroll
        for (int rt = 0; rt < 4; ++rt) a1[rt][n] = MFMA16(A[rt], B, a1[rt][n]);
      }
    }
#pragma unroll
    for (int n = 0; n < 4; ++n) {
      float bb = b_in1[(4 * wid + n) * 16 + lr];
#pragma unroll
      for (int rt = 0; rt < 4; ++rt)
#pragma unroll
        for (int j = 0; j < 4; ++j) {
          int r = 16 * rt + lg * 4 + j, c = (4 * wid + n) * 16 + lr;
          F1s[(r * 256 + c) ^ ((r & 7) << 3)] = f2bf(fmaxf(a1[rt][n][j] + bb, 0.f));
        }
    }
  }
  __syncthreads();

  { // L2: [64,128], K=256
    f32x4 a2[4][2] = {};
#pragma unroll
    for (int kf = 0; kf < 8; ++kf) {
      bf16x8 A[4];
#pragma unroll
      for (int rt = 0; rt < 4; ++rt) {
        int r = 16 * rt + lr;
        A[rt] = *(const bf16x8*)&F1s[(r * 256 + (kf * 4 + lg) * 8) ^ ((r & 7) << 3)];
      }
#pragma unroll
      for (int n = 0; n < 2; ++n) {
        bf16x8 B = *(const bf16x8*)(wsu + W2_U + (size_t)(((2 * wid + n) * 8 + kf) * 512) + lane * 8);
#pragma unroll
        for (int rt = 0; rt < 4; ++rt) a2[rt][n] = MFMA16(A[rt], B, a2[rt][n]);
      }
    }
#pragma unroll
    for (int n = 0; n < 2; ++n) {
      float bb = b_in2[(2 * wid + n) * 16 + lr];
#pragma unroll
      for (int rt = 0; rt < 4; ++rt)
#pragma unroll
        for (int j = 0; j < 4; ++j) {
          int r = 16 * rt + lg * 4 + j, c = (2 * wid + n) * 16 + lr;
          F2s[(r * 128 + c) ^ ((r & 7) << 3)] = f2bf(fmaxf(a2[rt][n][j] + bb, 0.f));
        }
    }
  }
  __syncthreads();

  { // L3: [64,128], K=128 -> XLs
    f32x4 a3[4][2] = {};
#pragma unroll
    for (int kf = 0; kf < 4; ++kf) {
      bf16x8 A[4];
#pragma unroll
      for (int rt = 0; rt < 4; ++rt) {
        int r = 16 * rt + lr;
        A[rt] = *(const bf16x8*)&F2s[(r * 128 + (kf * 4 + lg) * 8) ^ ((r & 7) << 3)];
      }
#pragma unroll
      for (int n = 0; n < 2; ++n) {
        bf16x8 B = *(const bf16x8*)(wsu + W3_U + (size_t)(((2 * wid + n) * 4 + kf) * 512) + lane * 8);
#pragma unroll
        for (int rt = 0; rt < 4; ++rt) a3[rt][n] = MFMA16(A[rt], B, a3[rt][n]);
      }
    }
#pragma unroll
    for (int n = 0; n < 2; ++n) {
      float bb = b_in3[(2 * wid + n) * 16 + lr];
#pragma unroll
      for (int rt = 0; rt < 4; ++rt)
#pragma unroll
        for (int j = 0; j < 4; ++j) {
          int r = 16 * rt + lg * 4 + j, c = (2 * wid + n) * 16 + lr;
          XLs[(r * 128 + c) ^ ((r & 7) << 3)] = f2bf(fmaxf(a3[rt][n][j] + bb, 0.f));
        }
    }
  }
  __syncthreads();

  { // L4: g1x = x @ Wih1^T + bs1 : [64,512], K=128 -> global (fragment order)
    f32x4 a4[4][8] = {};
#pragma unroll
    for (int kf = 0; kf < 4; ++kf) {
      bf16x8 A[4];
#pragma unroll
      for (int rt = 0; rt < 4; ++rt) {
        int r = 16 * rt + lr;
        A[rt] = *(const bf16x8*)&XLs[(r * 128 + (kf * 4 + lg) * 8) ^ ((r & 7) << 3)];
      }
#pragma unroll
      for (int n = 0; n < 8; ++n) {
        bf16x8 B = *(const bf16x8*)(wsu + WIH1_U + (size_t)(((wid * 8 + n) * 4 + kf) * 512) + lane * 8);
#pragma unroll
        for (int rt = 0; rt < 4; ++rt) a4[rt][n] = MFMA16(A[rt], B, a4[rt][n]);
      }
    }
    const int blk = bid_b >> 2, slg = bid_b & 3;
#pragma unroll
    for (int n = 0; n < 8; ++n) {
      float bb = bs1f[(wid * 8 + n) * 16 + lr];
#pragma unroll
      for (int j = 0; j < 4; ++j) {
        int tl = bid_t * 16 + lg * 4 + j;
        u16x4 o = { f2bf(a4[0][n][j] + bb), f2bf(a4[1][n][j] + bb),
                    f2bf(a4[2][n][j] + bb), f2bf(a4[3][n][j] + bb) };
        size_t au = (size_t)G1X_U +
            ((((((size_t)tl * 256 + blk) * 4 + slg) * 4 + wid) * 8 + n) * 16 + lr) * 4;
        *(u16x4*)(wsu + au) = o;
      }
    }
  }
}

// ======================= scan chunk ========================================
__global__ __launch_bounds__(512, 1)
void scan_chunk(u16* __restrict__ wsu, float* __restrict__ out,
                const float* __restrict__ b_out1, const float* __restrict__ b_out2,
                const float* __restrict__ b_out3, int last) {
  __shared__ u16 Wl[65536];                   // 128 KB Whh2 B-frags
  __shared__ u16 H1d[2][2048], H2d[2][2048];  // 16 KB

  float* wsf = (float*)wsu;
  const int tid = threadIdx.x;
  const int wid = tid >> 6, lane = tid & 63;
  const int lr = lane & 15, lg = lane >> 4;
  const int b0 = blockIdx.x * 16;
  const int blkid = blockIdx.x;
  const int r5 = tid >> 5, c5 = (tid & 31) * 4;
  const int swl = (r5 * 128 + c5) ^ ((r5 & 7) << 3);

  // ---- register weights (128 accum regs = per-wave accum budget) ----
  bf16x8 wA[4][4], wB[4][4];   // Whh1, Wih2
#pragma unroll
  for (int g = 0; g < 4; ++g)
#pragma unroll
    for (int kf = 0; kf < 4; ++kf) {
      wA[g][kf] = *(const bf16x8*)(wsu + WHH1_U + (size_t)(((wid * 4 + g) * 4 + kf) * 512) + lane * 8);
      wB[g][kf] = *(const bf16x8*)(wsu + WIH2_U + (size_t)(((wid * 4 + g) * 4 + kf) * 512) + lane * 8);
    }
#pragma unroll
  for (int g = 0; g < 4; ++g)
#pragma unroll
    for (int kf = 0; kf < 4; ++kf) {
      asm volatile("" : "+a"(wA[g][kf]));
      asm volatile("" : "+a"(wB[g][kf]));
    }

  // ---- Whh2 -> Wl ----
#pragma unroll
  for (int i = 0; i < 16; ++i)
    GLOAD_LDS(wsu + WHH2_U + (wid * 16 + i) * 512 + lane * 8, &Wl[(wid * 16 + i) * 512]);

  // ---- state ----
  *(u16x4*)&H1d[0][swl] = *(const u16x4*)(wsu + STH1_U + (size_t)(b0 + r5) * 128 + c5);
  *(u16x4*)&H2d[0][swl] = *(const u16x4*)(wsu + STH2_U + (size_t)(b0 + r5) * 128 + c5);
  float cs1[4], cs2[4], bc2[4];
#pragma unroll
  for (int j = 0; j < 4; ++j) {
    cs1[j] = wsf[C1_F + (size_t)(b0 + lg * 4 + j) * 128 + 16 * wid + lr];
    cs2[j] = wsf[C2_F + (size_t)(b0 + lg * 4 + j) * 128 + 16 * wid + lr];
  }
#pragma unroll
  for (int g = 0; g < 4; ++g) bc2[g] = wsf[BS2_F + g * 128 + 16 * wid + lr];

  // ---- g1x(0) prefetch ----
  const u16* gp = wsu + G1X_U + (size_t)blkid * 8192 + lg * 2048 + wid * 64 + lr * 4;
  u16x4 gx[4];
#pragma unroll
  for (int g = 0; g < 4; ++g)
    gx[g] = *(const u16x4*)(gp + g * 512);

  __syncthreads();   // staging + Wl drained

  auto frag = [&](const u16* buf, int kg) -> bf16x8 {
    return *(const bf16x8*)&buf[(lr * 128 + kg * 8) ^ ((lr & 7) << 3)];
  };

  // ================= 64-step scan, 1 barrier/step =================
#pragma unroll 2
  for (int tl = 0; tl < TC; ++tl) {
    const int p = tl & 1, q = p ^ 1;

    // -- phase 1: cell1 = g1x(t) + Whh1 * h1(t-1) --
    f32x4 acc[4];
#pragma unroll
    for (int g = 0; g < 4; ++g)
      acc[g] = (f32x4){ b2f(gx[g][0]), b2f(gx[g][1]), b2f(gx[g][2]), b2f(gx[g][3]) };
    if (tl < TC - 1) {   // prefetch g1x(t+1): full-step latency window
      const u16* gpt = gp + (size_t)(tl + 1) * 2097152;
#pragma unroll
      for (int g = 0; g < 4; ++g)
        gx[g] = *(const u16x4*)(gpt + g * 512);
    }
#pragma unroll
    for (int kf = 0; kf < 4; ++kf) {
      bf16x8 a = frag(H1d[p], kf * 4 + lg);   // streamed: 1 live A-frag
#pragma unroll
      for (int g = 0; g < 4; ++g) acc[g] = MFMA16(a, wA[g][kf], acc[g]);
    }
#pragma unroll
    for (int j = 0; j < 4; ++j) {
      float cn = fsig(acc[1][j]) * cs1[j] + fsig(acc[0][j]) * ftanh(acc[2][j]);
      cs1[j] = cn;
      int r = lg * 4 + j;
      H1d[q][(r * 128 + 16 * wid + lr) ^ ((r & 7) << 3)] = f2bf(fsig(acc[3][j]) * ftanh(cn));
    }
    LGKM_BAR;   // h1(t) visible; all reads of H1d[p] complete

    // -- phase 2: cell2 = bs2 + Wih2 * h1(t) + Whh2 * h2(t-1) --
    f32x4 acd[4];
#pragma unroll
    for (int g = 0; g < 4; ++g) acd[g] = (f32x4){ bc2[g], bc2[g], bc2[g], bc2[g] };
#pragma unroll
    for (int kf = 0; kf < 4; ++kf) {
      bf16x8 h1n = frag(H1d[q], kf * 4 + lg);
#pragma unroll
      for (int g = 0; g < 4; ++g) acd[g] = MFMA16(h1n, wB[g][kf], acd[g]);
    }
#pragma unroll
    for (int kf = 0; kf < 4; ++kf) {
      bf16x8 h2f = frag(H2d[p], kf * 4 + lg);
#pragma unroll
      for (int g = 0; g < 4; ++g) {
        bf16x8 B = *(const bf16x8*)&Wl[(((wid * 4 + g) * 4 + kf) * 512) + lane * 8];
        acd[g] = MFMA16(h2f, B, acd[g]);
      }
    }
#pragma unroll
    for (int j = 0; j < 4; ++j) {
      float cn = fsig(acd[1][j]) * cs2[j] + fsig(acd[0][j]) * ftanh(acd[2][j]);
      cs2[j] = cn;
      int r = lg * 4 + j;
      H2d[q][(r * 128 + 16 * wid + lr) ^ ((r & 7) << 3)] = f2bf(fsig(acd[3][j]) * ftanh(cn));
    }
    // pin gx here: loads had the whole step to land; pinned values cannot be
    // rematerialized at next phase1's use point (the R10 double-fetch bug).
#pragma unroll
    for (int g = 0; g < 4; ++g) asm volatile("" : "+v"(gx[g]));
    // no second barrier (parity argument: R8/R10 verified)
  }
  LGKM_BAR;   // final h writes visible (TC even -> state in [0] buffers)

  if (!last) {
    *(u16x4*)(wsu + STH1_U + (size_t)(b0 + r5) * 128 + c5) = *(const u16x4*)&H1d[0][swl];
    *(u16x4*)(wsu + STH2_U + (size_t)(b0 + r5) * 128 + c5) = *(const u16x4*)&H2d[0][swl];
#pragma unroll
    for (int j = 0; j < 4; ++j) {
      wsf[C1_F + (size_t)(b0 + lg * 4 + j) * 128 + 16 * wid + lr] = cs1[j];
      wsf[C2_F + (size_t)(b0 + lg * 4 + j) * 128 + 16 * wid + lr] = cs2[j];
    }
  } else {
    // ---- head: Y1 -> H1d[1]; Y2 -> H2d[1] (lo) | H1d[0] (hi); Y3 -> out ----
    {
      f32x4 y1 = {};
#pragma unroll
      for (int kf = 0; kf < 4; ++kf) {
        bf16x8 A = frag(H2d[0], kf * 4 + lg);
        bf16x8 B = *(const bf16x8*)(wsu + WO1_U + (size_t)((wid * 4 + kf) * 512) + lane * 8);
        y1 = MFMA16(A, B, y1);
      }
      float bo1 = b_out1[wid * 16 + lr];
      LGKM_BAR;
#pragma unroll
      for (int j = 0; j < 4; ++j) {
        int r = lg * 4 + j;
        H1d[1][(r * 128 + 16 * wid + lr) ^ ((r & 7) << 3)] = f2bf(fmaxf(y1[j] + bo1, 0.f));
      }
      LGKM_BAR;
    }
    {
      f32x4 y2[2] = {};
#pragma unroll
      for (int kf = 0; kf < 4; ++kf) {
        bf16x8 A = frag(H1d[1], kf * 4 + lg);
#pragma unroll
        for (int n = 0; n < 2; ++n) {
          bf16x8 B = *(const bf16x8*)(wsu + WO2_U + (size_t)(((2 * wid + n) * 4 + kf) * 512) + lane * 8);
          y2[n] = MFMA16(A, B, y2[n]);
        }
      }
      LGKM_BAR;
#pragma unroll
      for (int n = 0; n < 2; ++n)
#pragma unroll
        for (int j = 0; j < 4; ++j) {
          int c = (2 * wid + n) * 16 + lr;
          float v = fmaxf(y2[n][j] + b_out2[c], 0.f);
          u16* buf = (c < 128) ? &H2d[1][0] : &H1d[0][0];
          int cc = c & 127, r = lg * 4 + j;
          buf[(r * 128 + cc) ^ ((r & 7) << 3)] = f2bf(v);
        }
      LGKM_BAR;
    }
    if (wid < 2) {
      f32x4 y3 = {};
#pragma unroll
      for (int kf = 0; kf < 8; ++kf) {
        const u16* ab = (kf < 4) ? &H2d[1][0] : &H1d[0][0];
        bf16x8 A = frag(ab, (kf & 3) * 4 + lg);
        bf16x8 B = *(const bf16x8*)(wsu + WO3_U + (size_t)((wid * 8 + kf) * 512) + lane * 8);
        y3 = MFMA16(A, B, y3);
      }
      float bo3 = b_out3[wid * 16 + lr];
#pragma unroll
      for (int j = 0; j < 4; ++j)
        out[(size_t)(b0 + lg * 4 + j) * 32 + wid * 16 + lr] = y3[j] + bo3;
    }
  }
}

// ======================= host ==============================================
extern "C" void kernel_launch(void* const* d_in, const int* in_sizes, int n_in,
                              void* d_out, int out_size, void* d_ws, size_t ws_size,
                              hipStream_t stream) {
  (void)in_sizes; (void)n_in; (void)out_size; (void)ws_size;
  const float* seq    = (const float*)d_in[0];
  const float* h1     = (const float*)d_in[1];
  const float* c1     = (const float*)d_in[2];
  const float* h2     = (const float*)d_in[3];
  const float* c2     = (const float*)d_in[4];
  const float* W_in1  = (const float*)d_in[5];
  const float* b_in1  = (const float*)d_in[6];
  const float* W_in2  = (const float*)d_in[7];
  const float* b_in2  = (const float*)d_in[8];
  const float* W_in3  = (const float*)d_in[9];
  const float* b_in3  = (const float*)d_in[10];
  const float* Wih1   = (const float*)d_in[11];
  const float* Whh1   = (const float*)d_in[12];
  const float* bih1   = (const float*)d_in[13];
  const float* bhh1   = (const float*)d_in[14];
  const float* Wih2   = (const float*)d_in[15];
  const float* Whh2   = (const float*)d_in[16];
  const float* bih2   = (const float*)d_in[17];
  const float* bhh2   = (const float*)d_in[18];
  const float* W_out1 = (const float*)d_in[19];
  const float* b_out1 = (const float*)d_in[20];
  const float* W_out2 = (const float*)d_in[21];
  const float* b_out2 = (const float*)d_in[22];
  const float* W_out3 = (const float*)d_in[23];
  const float* b_out3 = (const float*)d_in[24];
  u16* wsu = (u16*)d_ws;
  float* out = (float*)d_out;

  hipLaunchKernelGGL(prep_kernel, dim3(512), dim3(256), 0, stream,
                     Wih1, Whh1, bih1, bhh1, Wih2, Whh2, bih2, bhh2,
                     W_in1, W_in2, W_in3, W_out1, W_out2, W_out3,
                     h1, h2, c1, c2, wsu);
  for (int k = 0; k < NCH; ++k) {
    hipLaunchKernelGGL(fc_chunk, dim3(4096), dim3(256), 0, stream,
                       seq, b_in1, b_in2, b_in3, wsu, k * TC);
    hipLaunchKernelGGL(scan_chunk, dim3(256), dim3(512), 0, stream,
                       wsu, out, b_out1, b_out2, b_out3, (k == NCH - 1) ? 1 : 0);
  }
}